// Round 3
// baseline (122.718 us; speedup 1.0000x reference)
//
#include <hip/hip_runtime.h>
#include <hip/hip_bf16.h>

typedef short short8 __attribute__((ext_vector_type(8)));
typedef float f32x4 __attribute__((ext_vector_type(4)));
typedef unsigned int u32x4 __attribute__((ext_vector_type(4)));

#define MFMA16(a, b, c) __builtin_amdgcn_mfma_f32_16x16x32_bf16(a, b, c, 0, 0, 0)

__device__ __forceinline__ unsigned short f2bf(float f) {
    unsigned int u = __float_as_uint(f);
    unsigned int r = (u + 0x7fffu + ((u >> 16) & 1u)) >> 16;
    return (unsigned short)r;
}

__device__ __forceinline__ float fexp2(float x) {
#if __has_builtin(__builtin_amdgcn_exp2f)
    return __builtin_amdgcn_exp2f(x);
#else
    return exp2f(x);
#endif
}

__device__ __forceinline__ unsigned int cvtpk(float lo, float hi) {
    unsigned int r;
    asm("v_cvt_pk_bf16_f32 %0, %1, %2" : "=v"(r) : "v"(lo), "v"(hi));
    return r;
}

// q scale: hd^-0.5 * log2(e)  (softmax in base-2 domain, no max subtraction)
#define QSC (0.17677669529663687f * 1.4426950408889634f)

// ---------------- prep: weights fp32->bf16 + x transpose, fused ----------------
__global__ __launch_bounds__(256) void k_prep(const float* __restrict__ qkv_w,
                                              const float* __restrict__ proj_w,
                                              const float* __restrict__ x,
                                              unsigned short* __restrict__ wqb,
                                              unsigned short* __restrict__ pwb,
                                              unsigned short* __restrict__ xtb) {
    __shared__ float lds[64][65];
    int t = threadIdx.x;
    if (blockIdx.x < 256) {
        int i = (blockIdx.x * 256 + t) * 4;
        const int NQ = 768 * 256;
        const float* src;
        unsigned short* dst;
        if (i < NQ) { src = qkv_w + i; dst = wqb + i; }
        else        { src = proj_w + (i - NQ); dst = pwb + (i - NQ); }
        float4 v = *reinterpret_cast<const float4*>(src);
        ushort4 p;
        p.x = f2bf(v.x); p.y = f2bf(v.y); p.z = f2bf(v.z); p.w = f2bf(v.w);
        *reinterpret_cast<ushort4*>(dst) = p;
        return;
    }
    int bid = blockIdx.x - 256;
    int nt = bid & 63;   // n-tile
    int ct = bid >> 6;   // c-tile
    {
        int cc = t >> 2, nseg = t & 3;
        const float* src = x + (ct * 64 + cc) * 4096 + nt * 64 + nseg * 16;
#pragma unroll
        for (int k2 = 0; k2 < 4; ++k2) {
            float4 v = *reinterpret_cast<const float4*>(src + 4 * k2);
            lds[cc][nseg * 16 + 4 * k2 + 0] = v.x;
            lds[cc][nseg * 16 + 4 * k2 + 1] = v.y;
            lds[cc][nseg * 16 + 4 * k2 + 2] = v.z;
            lds[cc][nseg * 16 + 4 * k2 + 3] = v.w;
        }
    }
    __syncthreads();
    {
        int nn = t >> 2, seg = t & 3;
        unsigned short o[16];
#pragma unroll
        for (int j = 0; j < 16; ++j) o[j] = f2bf(lds[seg * 16 + j][nn]);
        unsigned short* dst = xtb + (nt * 64 + nn) * 256 + ct * 64 + seg * 16;
#pragma unroll
        for (int k2 = 0; k2 < 4; ++k2) {
            ushort4 p;
            p.x = o[4 * k2 + 0]; p.y = o[4 * k2 + 1]; p.z = o[4 * k2 + 2]; p.w = o[4 * k2 + 3];
            *reinterpret_cast<ushort4*>(dst + 4 * k2) = p;
        }
    }
}

// ---------------- QKV GEMM: [768][256] x [256][4096] -> scatter q/k/v bf16 ----------------
// q,k stored [h][n][32] (q pre-scaled by hd^-0.5*log2e), v stored [h*32+d][n]
__global__ __launch_bounds__(256) void k_qkv(const unsigned short* __restrict__ wqb,
                                             const unsigned short* __restrict__ xtb,
                                             unsigned short* __restrict__ qws,
                                             unsigned short* __restrict__ kws,
                                             unsigned short* __restrict__ vws) {
    int nt = blockIdx.x;           // 0..63 : n tile of 64
    int ot = blockIdx.y;           // 0..5  : o tile of 128
    int w = threadIdx.x >> 6;
    int l = threadIdx.x & 63;
    int lr = l & 15, lg = l >> 4;
    int obase = ot * 128 + w * 32;
    int nbase = nt * 64;

    f32x4 acc[2][4];
#pragma unroll
    for (int mi = 0; mi < 2; ++mi)
#pragma unroll
        for (int ni = 0; ni < 4; ++ni) acc[mi][ni] = (f32x4){0.f, 0.f, 0.f, 0.f};

#pragma unroll
    for (int ks = 0; ks < 8; ++ks) {
        short8 a[2], b[4];
#pragma unroll
        for (int mi = 0; mi < 2; ++mi)
            a[mi] = *reinterpret_cast<const short8*>(wqb + (obase + mi * 16 + lr) * 256 + ks * 32 + lg * 8);
#pragma unroll
        for (int ni = 0; ni < 4; ++ni)
            b[ni] = *reinterpret_cast<const short8*>(xtb + (nbase + ni * 16 + lr) * 256 + ks * 32 + lg * 8);
#pragma unroll
        for (int mi = 0; mi < 2; ++mi)
#pragma unroll
            for (int ni = 0; ni < 4; ++ni)
                acc[mi][ni] = MFMA16(a[mi], b[ni], acc[mi][ni]);
    }

#pragma unroll
    for (int mi = 0; mi < 2; ++mi) {
        int o0 = obase + mi * 16 + lg * 4;   // rows o0..o0+3
#pragma unroll
        for (int ni = 0; ni < 4; ++ni) {
            int n = nbase + ni * 16 + lr;
            f32x4 v = acc[mi][ni];
            if (o0 < 512) {
                float sc = (o0 < 256) ? QSC : 1.0f;
                unsigned short* base = (o0 < 256) ? qws : kws;
                int oo = o0 & 255;
                int h = oo >> 5, d0 = oo & 31;
                ushort4 pk;
                pk.x = f2bf(v[0] * sc); pk.y = f2bf(v[1] * sc);
                pk.z = f2bf(v[2] * sc); pk.w = f2bf(v[3] * sc);
                *reinterpret_cast<ushort4*>(base + h * 131072 + n * 32 + d0) = pk;
            } else {
                int oo = o0 - 512;
#pragma unroll
                for (int r = 0; r < 4; ++r) vws[(oo + r) * 4096 + n] = f2bf(v[r]);
            }
        }
    }
}

// ---------------- flash attention, LDS-free, no-max softmax, split-K ----------------
// Wave handles 16 q-rows. S computed transposed (A=K perm, B=Q) so each lane owns
// one q-row; P-frag for PV is pure in-lane cvt_pk. O^T = V^T P^T. No per-iter
// cross-lane ops: l reduced once after the loop. Partials (O', l) -> combine.
__global__ __launch_bounds__(256, 8) void k_attn(const unsigned short* __restrict__ qws,
                                                 const unsigned short* __restrict__ kws,
                                                 const unsigned short* __restrict__ vws,
                                                 float* __restrict__ opart,
                                                 float* __restrict__ oml) {
    int qs = blockIdx.x;   // 0..63 : 64-row tile (4 waves x 16)
    int h  = blockIdx.y;   // 0..7
    int sp = blockIdx.z;   // 0..3  : key split (1024 keys each)
    int t = threadIdx.x;
    int w = t >> 6, l = t & 63, lr = l & 15, lg = l >> 4;

    const unsigned short* qh = qws + h * 131072;
    const unsigned short* kh = kws + h * 131072;
    const unsigned short* vh = vws + h * 131072;

    int qb = qs * 64 + w * 16;
    short8 bq = *reinterpret_cast<const short8*>(qh + (qb + lr) * 32 + lg * 8);

    f32x4 o0 = {0.f, 0.f, 0.f, 0.f}, o1 = {0.f, 0.f, 0.f, 0.f};
    f32x4 lacc = {0.f, 0.f, 0.f, 0.f};

    // K A-frag key-row permutation: rows {8*(lr>>2)+(lr&3)} + {0,4,32,36}
    // composes with the P-pack so PV B-frag slot j == actual key j (identity).
    int krow = 8 * (lr >> 2) + (lr & 3);
    const unsigned short* kp = kh + krow * 32 + lg * 8;
    const unsigned short* vp = vh + lr * 4096 + lg * 8;

    int mt1 = sp * 16 + 16;
    for (int mt = sp * 16; mt < mt1; ++mt) {
        const unsigned short* b = kp + mt * 2048;
        short8 ka0 = *reinterpret_cast<const short8*>(b);
        short8 ka1 = *reinterpret_cast<const short8*>(b + 128);
        short8 ka2 = *reinterpret_cast<const short8*>(b + 1024);
        short8 ka3 = *reinterpret_cast<const short8*>(b + 1152);

        const f32x4 z = {0.f, 0.f, 0.f, 0.f};
        f32x4 s0 = MFMA16(ka0, bq, z);
        f32x4 s1 = MFMA16(ka1, bq, z);
        f32x4 s2 = MFMA16(ka2, bq, z);
        f32x4 s3 = MFMA16(ka3, bq, z);

#pragma unroll
        for (int e = 0; e < 4; ++e) {
            s0[e] = fexp2(s0[e]); s1[e] = fexp2(s1[e]);
            s2[e] = fexp2(s2[e]); s3[e] = fexp2(s3[e]);
        }
        lacc += (s0 + s1) + (s2 + s3);

        union { u32x4 u; short8 s8; } p0, p1;
        p0.u[0] = cvtpk(s0[0], s0[1]); p0.u[1] = cvtpk(s0[2], s0[3]);
        p0.u[2] = cvtpk(s1[0], s1[1]); p0.u[3] = cvtpk(s1[2], s1[3]);
        p1.u[0] = cvtpk(s2[0], s2[1]); p1.u[1] = cvtpk(s2[2], s2[3]);
        p1.u[2] = cvtpk(s3[0], s3[1]); p1.u[3] = cvtpk(s3[2], s3[3]);

        const unsigned short* vb = vp + mt * 64;
        short8 va00 = *reinterpret_cast<const short8*>(vb);
        short8 va01 = *reinterpret_cast<const short8*>(vb + 32);
        short8 va10 = *reinterpret_cast<const short8*>(vb + 65536);
        short8 va11 = *reinterpret_cast<const short8*>(vb + 65536 + 32);

        o0 = MFMA16(va00, p0.s8, o0);
        o0 = MFMA16(va01, p1.s8, o0);
        o1 = MFMA16(va10, p0.s8, o1);
        o1 = MFMA16(va11, p1.s8, o1);
    }

    float lsum = (lacc[0] + lacc[1]) + (lacc[2] + lacc[3]);
    lsum += __shfl_xor(lsum, 16);
    lsum += __shfl_xor(lsum, 32);

    int q = qb + lr;
    float* ob = opart + ((h * 4096 + q) * 4 + sp) * 32;
    *reinterpret_cast<f32x4*>(ob + lg * 4) = o0;
    *reinterpret_cast<f32x4*>(ob + 16 + lg * 4) = o1;
    oml[(h * 4096 + q) * 4 + sp] = lsum;   // lg-duplicate writes, identical value
}

// ---------------- combine split-K partials -> ao bf16 [n][256] ----------------
__global__ __launch_bounds__(256) void k_comb(const float* __restrict__ opart,
                                              const float* __restrict__ oml,
                                              unsigned short* __restrict__ ao) {
    int t = blockIdx.x * 256 + threadIdx.x;  // 131072 threads
    int hq = t >> 2;                         // 0..32767
    int dg = (t & 3) * 8;                    // d base
    f32x4 lv = *reinterpret_cast<const f32x4*>(oml + hq * 4);
    float inv = 1.0f / ((lv[0] + lv[1]) + (lv[2] + lv[3]));

    const float* ob = opart + hq * 128 + dg;
    f32x4 acc0 = (*reinterpret_cast<const f32x4*>(ob) + *reinterpret_cast<const f32x4*>(ob + 32)) +
                 (*reinterpret_cast<const f32x4*>(ob + 64) + *reinterpret_cast<const f32x4*>(ob + 96));
    f32x4 acc1 = (*reinterpret_cast<const f32x4*>(ob + 4) + *reinterpret_cast<const f32x4*>(ob + 36)) +
                 (*reinterpret_cast<const f32x4*>(ob + 68) + *reinterpret_cast<const f32x4*>(ob + 100));

    int h = hq >> 12, q = hq & 4095;
    unsigned short* dst = ao + q * 256 + h * 32 + dg;
    ushort4 pk;
    pk.x = f2bf(acc0[0] * inv); pk.y = f2bf(acc0[1] * inv);
    pk.z = f2bf(acc0[2] * inv); pk.w = f2bf(acc0[3] * inv);
    *reinterpret_cast<ushort4*>(dst) = pk;
    pk.x = f2bf(acc1[0] * inv); pk.y = f2bf(acc1[1] * inv);
    pk.z = f2bf(acc1[2] * inv); pk.w = f2bf(acc1[3] * inv);
    *reinterpret_cast<ushort4*>(dst + 4) = pk;
}

// ---------------- proj GEMM: [256][256] x ao^T + bias -> out fp32 [256][4096] ----------------
__global__ __launch_bounds__(256) void k_proj(const unsigned short* __restrict__ pwb,
                                              const unsigned short* __restrict__ ao,
                                              const float* __restrict__ bias,
                                              float* __restrict__ out) {
    int nt = blockIdx.x;   // 0..63
    int ot = blockIdx.y;   // 0..1
    int w = threadIdx.x >> 6;
    int l = threadIdx.x & 63;
    int lr = l & 15, lg = l >> 4;
    int obase = ot * 128 + w * 32;
    int nbase = nt * 64;

    f32x4 acc[2][4];
#pragma unroll
    for (int mi = 0; mi < 2; ++mi)
#pragma unroll
        for (int ni = 0; ni < 4; ++ni) acc[mi][ni] = (f32x4){0.f, 0.f, 0.f, 0.f};

#pragma unroll
    for (int ks = 0; ks < 8; ++ks) {
        short8 a[2], b[4];
#pragma unroll
        for (int mi = 0; mi < 2; ++mi)
            a[mi] = *reinterpret_cast<const short8*>(pwb + (obase + mi * 16 + lr) * 256 + ks * 32 + lg * 8);
#pragma unroll
        for (int ni = 0; ni < 4; ++ni)
            b[ni] = *reinterpret_cast<const short8*>(ao + (nbase + ni * 16 + lr) * 256 + ks * 32 + lg * 8);
#pragma unroll
        for (int mi = 0; mi < 2; ++mi)
#pragma unroll
            for (int ni = 0; ni < 4; ++ni)
                acc[mi][ni] = MFMA16(a[mi], b[ni], acc[mi][ni]);
    }

#pragma unroll
    for (int mi = 0; mi < 2; ++mi) {
        int o0 = obase + mi * 16 + lg * 4;
        float b0 = bias[o0 + 0], b1 = bias[o0 + 1], b2 = bias[o0 + 2], b3 = bias[o0 + 3];
#pragma unroll
        for (int ni = 0; ni < 4; ++ni) {
            int n = nbase + ni * 16 + lr;
            out[(o0 + 0) * 4096 + n] = acc[mi][ni][0] + b0;
            out[(o0 + 1) * 4096 + n] = acc[mi][ni][1] + b1;
            out[(o0 + 2) * 4096 + n] = acc[mi][ni][2] + b2;
            out[(o0 + 3) * 4096 + n] = acc[mi][ni][3] + b3;
        }
    }
}

extern "C" void kernel_launch(void* const* d_in, const int* in_sizes, int n_in,
                              void* d_out, int out_size, void* d_ws, size_t ws_size,
                              hipStream_t stream) {
    const float* x      = (const float*)d_in[0];
    const float* qkv_w  = (const float*)d_in[1];
    const float* proj_w = (const float*)d_in[2];
    const float* proj_b = (const float*)d_in[3];
    float* out = (float*)d_out;

    char* ws = (char*)d_ws;
    unsigned short* wqb = (unsigned short*)(ws + 0);         // 768*256*2   = 393216
    unsigned short* pwb = (unsigned short*)(ws + 393216);    // 256*256*2   = 131072
    unsigned short* xtb = (unsigned short*)(ws + 524288);    // 4096*256*2  = 2097152
    unsigned short* qws = (unsigned short*)(ws + 2621440);   // 8*4096*32*2 = 2097152
    unsigned short* kws = (unsigned short*)(ws + 4718592);   // 2097152
    unsigned short* vws = (unsigned short*)(ws + 6815744);   // 2097152
    unsigned short* ao  = (unsigned short*)(ws + 8912896);   // 4096*256*2  = 2097152
    float* opart        = (float*)(ws + 11010048);           // 8*4096*4*32*4 = 16777216
    float* oml          = (float*)(ws + 27787264);           // 8*4096*4*4   = 524288

    k_prep<<<512, 256, 0, stream>>>(qkv_w, proj_w, x, wqb, pwb, xtb);
    k_qkv<<<dim3(64, 6), 256, 0, stream>>>(wqb, xtb, qws, kws, vws);
    k_attn<<<dim3(64, 8, 4), 256, 0, stream>>>(qws, kws, vws, opart, oml);
    k_comb<<<512, 256, 0, stream>>>(opart, oml, ao);
    k_proj<<<dim3(64, 2), 256, 0, stream>>>(pwb, ao, proj_b, out);
}

// Round 4
// 85.510 us; speedup vs baseline: 1.4351x; 1.4351x over previous
//
#include <hip/hip_runtime.h>
#include <hip/hip_bf16.h>

typedef short short8 __attribute__((ext_vector_type(8)));
typedef float f32x4 __attribute__((ext_vector_type(4)));
typedef unsigned int u32x4 __attribute__((ext_vector_type(4)));

#define MFMA16(a, b, c) __builtin_amdgcn_mfma_f32_16x16x32_bf16(a, b, c, 0, 0, 0)

__device__ __forceinline__ unsigned short f2bf(float f) {
    unsigned int u = __float_as_uint(f);
    unsigned int r = (u + 0x7fffu + ((u >> 16) & 1u)) >> 16;
    return (unsigned short)r;
}

__device__ __forceinline__ float fexp2(float x) {
#if __has_builtin(__builtin_amdgcn_exp2f)
    return __builtin_amdgcn_exp2f(x);
#else
    return exp2f(x);
#endif
}

__device__ __forceinline__ unsigned int cvtpk(float lo, float hi) {
    unsigned int r;
    asm("v_cvt_pk_bf16_f32 %0, %1, %2" : "=v"(r) : "v"(lo), "v"(hi));
    return r;
}

__device__ __forceinline__ float hsum4(f32x4 a) { return (a[0] + a[1]) + (a[2] + a[3]); }

// q scale: hd^-0.5 * log2(e)  (softmax in base-2 domain, no max subtraction)
#define QSC (0.17677669529663687f * 1.4426950408889634f)

// ---------------- prep: weights fp32->bf16 + x transpose, fused ----------------
__global__ __launch_bounds__(256) void k_prep(const float* __restrict__ qkv_w,
                                              const float* __restrict__ proj_w,
                                              const float* __restrict__ x,
                                              unsigned short* __restrict__ wqb,
                                              unsigned short* __restrict__ pwb,
                                              unsigned short* __restrict__ xtb) {
    __shared__ float lds[64][65];
    int t = threadIdx.x;
    if (blockIdx.x < 256) {
        int i = (blockIdx.x * 256 + t) * 4;
        const int NQ = 768 * 256;
        const float* src;
        unsigned short* dst;
        if (i < NQ) { src = qkv_w + i; dst = wqb + i; }
        else        { src = proj_w + (i - NQ); dst = pwb + (i - NQ); }
        float4 v = *reinterpret_cast<const float4*>(src);
        ushort4 p;
        p.x = f2bf(v.x); p.y = f2bf(v.y); p.z = f2bf(v.z); p.w = f2bf(v.w);
        *reinterpret_cast<ushort4*>(dst) = p;
        return;
    }
    int bid = blockIdx.x - 256;
    int nt = bid & 63;   // n-tile
    int ct = bid >> 6;   // c-tile
    {
        int cc = t >> 2, nseg = t & 3;
        const float* src = x + (ct * 64 + cc) * 4096 + nt * 64 + nseg * 16;
#pragma unroll
        for (int k2 = 0; k2 < 4; ++k2) {
            float4 v = *reinterpret_cast<const float4*>(src + 4 * k2);
            lds[cc][nseg * 16 + 4 * k2 + 0] = v.x;
            lds[cc][nseg * 16 + 4 * k2 + 1] = v.y;
            lds[cc][nseg * 16 + 4 * k2 + 2] = v.z;
            lds[cc][nseg * 16 + 4 * k2 + 3] = v.w;
        }
    }
    __syncthreads();
    {
        int nn = t >> 2, seg = t & 3;
        unsigned short o[16];
#pragma unroll
        for (int j = 0; j < 16; ++j) o[j] = f2bf(lds[seg * 16 + j][nn]);
        unsigned short* dst = xtb + (nt * 64 + nn) * 256 + ct * 64 + seg * 16;
#pragma unroll
        for (int k2 = 0; k2 < 4; ++k2) {
            ushort4 p;
            p.x = o[4 * k2 + 0]; p.y = o[4 * k2 + 1]; p.z = o[4 * k2 + 2]; p.w = o[4 * k2 + 3];
            *reinterpret_cast<ushort4*>(dst + 4 * k2) = p;
        }
    }
}

// ---------------- QKV GEMM: [768][256] x [256][4096] -> scatter q/k/v bf16 ----------------
// q,k stored [h][n][32] (q pre-scaled by hd^-0.5*log2e), v stored [h*32+d][n]
__global__ __launch_bounds__(256) void k_qkv(const unsigned short* __restrict__ wqb,
                                             const unsigned short* __restrict__ xtb,
                                             unsigned short* __restrict__ qws,
                                             unsigned short* __restrict__ kws,
                                             unsigned short* __restrict__ vws) {
    int nt = blockIdx.x;           // 0..63 : n tile of 64
    int ot = blockIdx.y;           // 0..5  : o tile of 128
    int w = threadIdx.x >> 6;
    int l = threadIdx.x & 63;
    int lr = l & 15, lg = l >> 4;
    int obase = ot * 128 + w * 32;
    int nbase = nt * 64;

    f32x4 acc[2][4];
#pragma unroll
    for (int mi = 0; mi < 2; ++mi)
#pragma unroll
        for (int ni = 0; ni < 4; ++ni) acc[mi][ni] = (f32x4){0.f, 0.f, 0.f, 0.f};

#pragma unroll
    for (int ks = 0; ks < 8; ++ks) {
        short8 a[2], b[4];
#pragma unroll
        for (int mi = 0; mi < 2; ++mi)
            a[mi] = *reinterpret_cast<const short8*>(wqb + (obase + mi * 16 + lr) * 256 + ks * 32 + lg * 8);
#pragma unroll
        for (int ni = 0; ni < 4; ++ni)
            b[ni] = *reinterpret_cast<const short8*>(xtb + (nbase + ni * 16 + lr) * 256 + ks * 32 + lg * 8);
#pragma unroll
        for (int mi = 0; mi < 2; ++mi)
#pragma unroll
            for (int ni = 0; ni < 4; ++ni)
                acc[mi][ni] = MFMA16(a[mi], b[ni], acc[mi][ni]);
    }

#pragma unroll
    for (int mi = 0; mi < 2; ++mi) {
        int o0 = obase + mi * 16 + lg * 4;   // rows o0..o0+3
#pragma unroll
        for (int ni = 0; ni < 4; ++ni) {
            int n = nbase + ni * 16 + lr;
            f32x4 v = acc[mi][ni];
            if (o0 < 512) {
                float sc = (o0 < 256) ? QSC : 1.0f;
                unsigned short* base = (o0 < 256) ? qws : kws;
                int oo = o0 & 255;
                int h = oo >> 5, d0 = oo & 31;
                ushort4 pk;
                pk.x = f2bf(v[0] * sc); pk.y = f2bf(v[1] * sc);
                pk.z = f2bf(v[2] * sc); pk.w = f2bf(v[3] * sc);
                *reinterpret_cast<ushort4*>(base + h * 131072 + n * 32 + d0) = pk;
            } else {
                int oo = o0 - 512;
#pragma unroll
                for (int r = 0; r < 4; ++r) vws[(oo + r) * 4096 + n] = f2bf(v[r]);
            }
        }
    }
}

// ---------------- flash attention, LDS-free, no-max softmax, split-K ----------------
// Wave handles 32 q-rows (2 B-frags). S computed transposed (A=K perm, B=Q) so each
// lane owns 2 q-rows fully; P-frags are pure in-lane cvt_pk. O^T = V^T P^T.
// No per-iter cross-lane ops. Grid (h fastest) pins each head to one XCD's L2.
__global__ __launch_bounds__(256, 4) void k_attn(const unsigned short* __restrict__ qws,
                                                 const unsigned short* __restrict__ kws,
                                                 const unsigned short* __restrict__ vws,
                                                 float* __restrict__ opart,
                                                 float* __restrict__ oml) {
    int h  = blockIdx.x;   // 0..7  fastest -> linear%8==h -> per-XCD head affinity
    int qs = blockIdx.y;   // 0..31 : 128-row tile (4 waves x 32)
    int sp = blockIdx.z;   // 0..3  : key split (1024 keys each)
    int t = threadIdx.x;
    int w = t >> 6, l = t & 63, lr = l & 15, lg = l >> 4;

    const unsigned short* qh = qws + h * 131072;
    const unsigned short* kh = kws + h * 131072;
    const unsigned short* vh = vws + h * 131072;

    int qb = qs * 128 + w * 32;
    short8 bq0 = *reinterpret_cast<const short8*>(qh + (qb + lr) * 32 + lg * 8);
    short8 bq1 = *reinterpret_cast<const short8*>(qh + (qb + 16 + lr) * 32 + lg * 8);

    f32x4 o00 = {0.f,0.f,0.f,0.f}, o01 = o00, o10 = o00, o11 = o00; // o[j][dsub]
    f32x4 la0 = {0.f,0.f,0.f,0.f}, la1 = {0.f,0.f,0.f,0.f};

    // K A-frag key-row permutation: rows {8*(lr>>2)+(lr&3)} + {0,4,32,36}
    // composes with the P-pack so PV B-frag slot j == actual key j (identity).
    int krow = 8 * (lr >> 2) + (lr & 3);
    const unsigned short* kp = kh + krow * 32 + lg * 8;
    const unsigned short* vp = vh + lr * 4096 + lg * 8;

    int mt0 = sp * 16, mt1 = mt0 + 16;
    short8 ka0, ka1, ka2, ka3;
    {
        const unsigned short* b = kp + mt0 * 2048;
        ka0 = *reinterpret_cast<const short8*>(b);
        ka1 = *reinterpret_cast<const short8*>(b + 128);
        ka2 = *reinterpret_cast<const short8*>(b + 1024);
        ka3 = *reinterpret_cast<const short8*>(b + 1152);
    }

    for (int mt = mt0; mt < mt1; ++mt) {
        // V frags (independent, issue early)
        const unsigned short* vb = vp + mt * 64;
        short8 va00 = *reinterpret_cast<const short8*>(vb);
        short8 va01 = *reinterpret_cast<const short8*>(vb + 32);
        short8 va10 = *reinterpret_cast<const short8*>(vb + 65536);
        short8 va11 = *reinterpret_cast<const short8*>(vb + 65536 + 32);

        const f32x4 z = {0.f, 0.f, 0.f, 0.f};
        f32x4 s00 = MFMA16(ka0, bq0, z);
        f32x4 s01 = MFMA16(ka1, bq0, z);
        f32x4 s02 = MFMA16(ka2, bq0, z);
        f32x4 s03 = MFMA16(ka3, bq0, z);
        f32x4 s10 = MFMA16(ka0, bq1, z);
        f32x4 s11 = MFMA16(ka1, bq1, z);
        f32x4 s12 = MFMA16(ka2, bq1, z);
        f32x4 s13 = MFMA16(ka3, bq1, z);

        // prefetch next K tile under the softmax VALU work
        {
            int mtn = (mt + 1 < mt1) ? (mt + 1) : mt0;
            const unsigned short* b = kp + mtn * 2048;
            ka0 = *reinterpret_cast<const short8*>(b);
            ka1 = *reinterpret_cast<const short8*>(b + 128);
            ka2 = *reinterpret_cast<const short8*>(b + 1024);
            ka3 = *reinterpret_cast<const short8*>(b + 1152);
        }

#pragma unroll
        for (int e = 0; e < 4; ++e) {
            s00[e] = fexp2(s00[e]); s01[e] = fexp2(s01[e]);
            s02[e] = fexp2(s02[e]); s03[e] = fexp2(s03[e]);
            s10[e] = fexp2(s10[e]); s11[e] = fexp2(s11[e]);
            s12[e] = fexp2(s12[e]); s13[e] = fexp2(s13[e]);
        }
        la0 += (s00 + s01) + (s02 + s03);
        la1 += (s10 + s11) + (s12 + s13);

        union { u32x4 u; short8 s8; } p00, p01, p10, p11;
        p00.u[0] = cvtpk(s00[0], s00[1]); p00.u[1] = cvtpk(s00[2], s00[3]);
        p00.u[2] = cvtpk(s01[0], s01[1]); p00.u[3] = cvtpk(s01[2], s01[3]);
        p01.u[0] = cvtpk(s02[0], s02[1]); p01.u[1] = cvtpk(s02[2], s02[3]);
        p01.u[2] = cvtpk(s03[0], s03[1]); p01.u[3] = cvtpk(s03[2], s03[3]);
        p10.u[0] = cvtpk(s10[0], s10[1]); p10.u[1] = cvtpk(s10[2], s10[3]);
        p10.u[2] = cvtpk(s11[0], s11[1]); p10.u[3] = cvtpk(s11[2], s11[3]);
        p11.u[0] = cvtpk(s12[0], s12[1]); p11.u[1] = cvtpk(s12[2], s12[3]);
        p11.u[2] = cvtpk(s13[0], s13[1]); p11.u[3] = cvtpk(s13[2], s13[3]);

        o00 = MFMA16(va00, p00.s8, o00);
        o00 = MFMA16(va01, p01.s8, o00);
        o01 = MFMA16(va10, p00.s8, o01);
        o01 = MFMA16(va11, p01.s8, o01);
        o10 = MFMA16(va00, p10.s8, o10);
        o10 = MFMA16(va01, p11.s8, o10);
        o11 = MFMA16(va10, p10.s8, o11);
        o11 = MFMA16(va11, p11.s8, o11);
    }

    float ls0 = hsum4(la0);
    ls0 += __shfl_xor(ls0, 16);
    ls0 += __shfl_xor(ls0, 32);
    float ls1 = hsum4(la1);
    ls1 += __shfl_xor(ls1, 16);
    ls1 += __shfl_xor(ls1, 32);

    int q0 = qb + lr, q1 = qb + 16 + lr;
    float* ob0 = opart + ((h * 4096 + q0) * 4 + sp) * 32;
    float* ob1 = opart + ((h * 4096 + q1) * 4 + sp) * 32;
    __builtin_nontemporal_store(o00, reinterpret_cast<f32x4*>(ob0 + lg * 4));
    __builtin_nontemporal_store(o01, reinterpret_cast<f32x4*>(ob0 + 16 + lg * 4));
    __builtin_nontemporal_store(o10, reinterpret_cast<f32x4*>(ob1 + lg * 4));
    __builtin_nontemporal_store(o11, reinterpret_cast<f32x4*>(ob1 + 16 + lg * 4));
    oml[(h * 4096 + q0) * 4 + sp] = ls0;   // lg-duplicate writes, identical value
    oml[(h * 4096 + q1) * 4 + sp] = ls1;
}

// ---------------- combine split-K partials -> ao bf16 [n][256] ----------------
__global__ __launch_bounds__(256) void k_comb(const float* __restrict__ opart,
                                              const float* __restrict__ oml,
                                              unsigned short* __restrict__ ao) {
    int t = blockIdx.x * 256 + threadIdx.x;  // 131072 threads
    int hq = t >> 2;                         // 0..32767
    int dg = (t & 3) * 8;                    // d base
    f32x4 lv = *reinterpret_cast<const f32x4*>(oml + hq * 4);
    float inv = 1.0f / ((lv[0] + lv[1]) + (lv[2] + lv[3]));

    const float* ob = opart + hq * 128 + dg;
    f32x4 v0 = __builtin_nontemporal_load(reinterpret_cast<const f32x4*>(ob));
    f32x4 v1 = __builtin_nontemporal_load(reinterpret_cast<const f32x4*>(ob + 32));
    f32x4 v2 = __builtin_nontemporal_load(reinterpret_cast<const f32x4*>(ob + 64));
    f32x4 v3 = __builtin_nontemporal_load(reinterpret_cast<const f32x4*>(ob + 96));
    f32x4 acc0 = (v0 + v1) + (v2 + v3);
    v0 = __builtin_nontemporal_load(reinterpret_cast<const f32x4*>(ob + 4));
    v1 = __builtin_nontemporal_load(reinterpret_cast<const f32x4*>(ob + 36));
    v2 = __builtin_nontemporal_load(reinterpret_cast<const f32x4*>(ob + 68));
    v3 = __builtin_nontemporal_load(reinterpret_cast<const f32x4*>(ob + 100));
    f32x4 acc1 = (v0 + v1) + (v2 + v3);

    int h = hq >> 12, q = hq & 4095;
    unsigned short* dst = ao + q * 256 + h * 32 + dg;
    ushort4 pk;
    pk.x = f2bf(acc0[0] * inv); pk.y = f2bf(acc0[1] * inv);
    pk.z = f2bf(acc0[2] * inv); pk.w = f2bf(acc0[3] * inv);
    *reinterpret_cast<ushort4*>(dst) = pk;
    pk.x = f2bf(acc1[0] * inv); pk.y = f2bf(acc1[1] * inv);
    pk.z = f2bf(acc1[2] * inv); pk.w = f2bf(acc1[3] * inv);
    *reinterpret_cast<ushort4*>(dst + 4) = pk;
}

// ---------------- proj GEMM: [256][256] x ao^T + bias -> out fp32 [256][4096] ----------------
__global__ __launch_bounds__(256) void k_proj(const unsigned short* __restrict__ pwb,
                                              const unsigned short* __restrict__ ao,
                                              const float* __restrict__ bias,
                                              float* __restrict__ out) {
    int nt = blockIdx.x;   // 0..63
    int ot = blockIdx.y;   // 0..1
    int w = threadIdx.x >> 6;
    int l = threadIdx.x & 63;
    int lr = l & 15, lg = l >> 4;
    int obase = ot * 128 + w * 32;
    int nbase = nt * 64;

    f32x4 acc[2][4];
#pragma unroll
    for (int mi = 0; mi < 2; ++mi)
#pragma unroll
        for (int ni = 0; ni < 4; ++ni) acc[mi][ni] = (f32x4){0.f, 0.f, 0.f, 0.f};

#pragma unroll
    for (int ks = 0; ks < 8; ++ks) {
        short8 a[2], b[4];
#pragma unroll
        for (int mi = 0; mi < 2; ++mi)
            a[mi] = *reinterpret_cast<const short8*>(pwb + (obase + mi * 16 + lr) * 256 + ks * 32 + lg * 8);
#pragma unroll
        for (int ni = 0; ni < 4; ++ni)
            b[ni] = *reinterpret_cast<const short8*>(ao + (nbase + ni * 16 + lr) * 256 + ks * 32 + lg * 8);
#pragma unroll
        for (int mi = 0; mi < 2; ++mi)
#pragma unroll
            for (int ni = 0; ni < 4; ++ni)
                acc[mi][ni] = MFMA16(a[mi], b[ni], acc[mi][ni]);
    }

#pragma unroll
    for (int mi = 0; mi < 2; ++mi) {
        int o0 = obase + mi * 16 + lg * 4;
        float b0 = bias[o0 + 0], b1 = bias[o0 + 1], b2 = bias[o0 + 2], b3 = bias[o0 + 3];
#pragma unroll
        for (int ni = 0; ni < 4; ++ni) {
            int n = nbase + ni * 16 + lr;
            out[(o0 + 0) * 4096 + n] = acc[mi][ni][0] + b0;
            out[(o0 + 1) * 4096 + n] = acc[mi][ni][1] + b1;
            out[(o0 + 2) * 4096 + n] = acc[mi][ni][2] + b2;
            out[(o0 + 3) * 4096 + n] = acc[mi][ni][3] + b3;
        }
    }
}

extern "C" void kernel_launch(void* const* d_in, const int* in_sizes, int n_in,
                              void* d_out, int out_size, void* d_ws, size_t ws_size,
                              hipStream_t stream) {
    const float* x      = (const float*)d_in[0];
    const float* qkv_w  = (const float*)d_in[1];
    const float* proj_w = (const float*)d_in[2];
    const float* proj_b = (const float*)d_in[3];
    float* out = (float*)d_out;

    char* ws = (char*)d_ws;
    unsigned short* wqb = (unsigned short*)(ws + 0);         // 768*256*2   = 393216
    unsigned short* pwb = (unsigned short*)(ws + 393216);    // 256*256*2   = 131072
    unsigned short* xtb = (unsigned short*)(ws + 524288);    // 4096*256*2  = 2097152
    unsigned short* qws = (unsigned short*)(ws + 2621440);   // 8*4096*32*2 = 2097152
    unsigned short* kws = (unsigned short*)(ws + 4718592);   // 2097152
    unsigned short* vws = (unsigned short*)(ws + 6815744);   // 2097152
    unsigned short* ao  = (unsigned short*)(ws + 8912896);   // 4096*256*2  = 2097152
    float* opart        = (float*)(ws + 11010048);           // 8*4096*4*32*4 = 16777216
    float* oml          = (float*)(ws + 27787264);           // 8*4096*4*4   = 524288

    k_prep<<<512, 256, 0, stream>>>(qkv_w, proj_w, x, wqb, pwb, xtb);
    k_qkv<<<dim3(64, 6), 256, 0, stream>>>(wqb, xtb, qws, kws, vws);
    k_attn<<<dim3(8, 32, 4), 256, 0, stream>>>(qws, kws, vws, opart, oml);
    k_comb<<<512, 256, 0, stream>>>(opart, oml, ao);
    k_proj<<<dim3(64, 2), 256, 0, stream>>>(pwb, ao, proj_b, out);
}

// Round 6
// 62.482 us; speedup vs baseline: 1.9640x; 1.3686x over previous
//
#include <hip/hip_runtime.h>
#include <hip/hip_bf16.h>

typedef short short8 __attribute__((ext_vector_type(8)));
typedef unsigned short ushort8 __attribute__((ext_vector_type(8)));
typedef float f32x4 __attribute__((ext_vector_type(4)));
typedef unsigned int u32x4 __attribute__((ext_vector_type(4)));

#define MFMA16(a, b, c) __builtin_amdgcn_mfma_f32_16x16x32_bf16(a, b, c, 0, 0, 0)

__device__ __forceinline__ unsigned short f2bf(float f) {
    unsigned int u = __float_as_uint(f);
    unsigned int r = (u + 0x7fffu + ((u >> 16) & 1u)) >> 16;
    return (unsigned short)r;
}

__device__ __forceinline__ float fexp2(float x) {
#if __has_builtin(__builtin_amdgcn_exp2f)
    return __builtin_amdgcn_exp2f(x);
#else
    return exp2f(x);
#endif
}

__device__ __forceinline__ unsigned int cvtpk(float lo, float hi) {
    unsigned int r;
    asm("v_cvt_pk_bf16_f32 %0, %1, %2" : "=v"(r) : "v"(lo), "v"(hi));
    return r;
}

__device__ __forceinline__ float hsum4(f32x4 a) { return (a[0] + a[1]) + (a[2] + a[3]); }

// q scale: hd^-0.5 * log2(e)  (softmax in base-2 domain, no max subtraction)
#define QSC (0.17677669529663687f * 1.4426950408889634f)

// ---------------- prep: weights fp32->bf16 + x transpose, fused ----------------
__global__ __launch_bounds__(256) void k_prep(const float* __restrict__ qkv_w,
                                              const float* __restrict__ proj_w,
                                              const float* __restrict__ x,
                                              unsigned short* __restrict__ wqb,
                                              unsigned short* __restrict__ pwb,
                                              unsigned short* __restrict__ xtb) {
    __shared__ float lds[64][65];
    int t = threadIdx.x;
    if (blockIdx.x < 256) {
        int i = (blockIdx.x * 256 + t) * 4;
        const int NQ = 768 * 256;
        const float* src;
        unsigned short* dst;
        if (i < NQ) { src = qkv_w + i; dst = wqb + i; }
        else        { src = proj_w + (i - NQ); dst = pwb + (i - NQ); }
        float4 v = *reinterpret_cast<const float4*>(src);
        ushort4 p;
        p.x = f2bf(v.x); p.y = f2bf(v.y); p.z = f2bf(v.z); p.w = f2bf(v.w);
        *reinterpret_cast<ushort4*>(dst) = p;
        return;
    }
    int bid = blockIdx.x - 256;
    int nt = bid & 63;   // n-tile
    int ct = bid >> 6;   // c-tile
    {
        int cc = t >> 2, nseg = t & 3;
        const float* src = x + (ct * 64 + cc) * 4096 + nt * 64 + nseg * 16;
#pragma unroll
        for (int k2 = 0; k2 < 4; ++k2) {
            float4 v = *reinterpret_cast<const float4*>(src + 4 * k2);
            lds[cc][nseg * 16 + 4 * k2 + 0] = v.x;
            lds[cc][nseg * 16 + 4 * k2 + 1] = v.y;
            lds[cc][nseg * 16 + 4 * k2 + 2] = v.z;
            lds[cc][nseg * 16 + 4 * k2 + 3] = v.w;
        }
    }
    __syncthreads();
    {
        int nn = t >> 2, seg = t & 3;
        unsigned short o[16];
#pragma unroll
        for (int j = 0; j < 16; ++j) o[j] = f2bf(lds[seg * 16 + j][nn]);
        unsigned short* dst = xtb + (nt * 64 + nn) * 256 + ct * 64 + seg * 16;
#pragma unroll
        for (int k2 = 0; k2 < 4; ++k2) {
            ushort4 p;
            p.x = o[4 * k2 + 0]; p.y = o[4 * k2 + 1]; p.z = o[4 * k2 + 2]; p.w = o[4 * k2 + 3];
            *reinterpret_cast<ushort4*>(dst + 4 * k2) = p;
        }
    }
}

// ---------------- QKV GEMM: [768][256] x [256][4096] -> scatter q/k/v bf16 ----------------
// q,k stored [h][n][32] (q pre-scaled by hd^-0.5*log2e), v stored [h*32+d][n]
__global__ __launch_bounds__(256) void k_qkv(const unsigned short* __restrict__ wqb,
                                             const unsigned short* __restrict__ xtb,
                                             unsigned short* __restrict__ qws,
                                             unsigned short* __restrict__ kws,
                                             unsigned short* __restrict__ vws) {
    int nt = blockIdx.x;           // 0..63 : n tile of 64
    int ot = blockIdx.y;           // 0..5  : o tile of 128
    int w = threadIdx.x >> 6;
    int l = threadIdx.x & 63;
    int lr = l & 15, lg = l >> 4;
    int obase = ot * 128 + w * 32;
    int nbase = nt * 64;

    f32x4 acc[2][4];
#pragma unroll
    for (int mi = 0; mi < 2; ++mi)
#pragma unroll
        for (int ni = 0; ni < 4; ++ni) acc[mi][ni] = (f32x4){0.f, 0.f, 0.f, 0.f};

#pragma unroll
    for (int ks = 0; ks < 8; ++ks) {
        short8 a[2], b[4];
#pragma unroll
        for (int mi = 0; mi < 2; ++mi)
            a[mi] = *reinterpret_cast<const short8*>(wqb + (obase + mi * 16 + lr) * 256 + ks * 32 + lg * 8);
#pragma unroll
        for (int ni = 0; ni < 4; ++ni)
            b[ni] = *reinterpret_cast<const short8*>(xtb + (nbase + ni * 16 + lr) * 256 + ks * 32 + lg * 8);
#pragma unroll
        for (int mi = 0; mi < 2; ++mi)
#pragma unroll
            for (int ni = 0; ni < 4; ++ni)
                acc[mi][ni] = MFMA16(a[mi], b[ni], acc[mi][ni]);
    }

#pragma unroll
    for (int mi = 0; mi < 2; ++mi) {
        int o0 = obase + mi * 16 + lg * 4;   // rows o0..o0+3
#pragma unroll
        for (int ni = 0; ni < 4; ++ni) {
            int n = nbase + ni * 16 + lr;
            f32x4 v = acc[mi][ni];
            if (o0 < 512) {
                float sc = (o0 < 256) ? QSC : 1.0f;
                unsigned short* base = (o0 < 256) ? qws : kws;
                int oo = o0 & 255;
                int h = oo >> 5, d0 = oo & 31;
                ushort4 pk;
                pk.x = f2bf(v[0] * sc); pk.y = f2bf(v[1] * sc);
                pk.z = f2bf(v[2] * sc); pk.w = f2bf(v[3] * sc);
                *reinterpret_cast<ushort4*>(base + h * 131072 + n * 32 + d0) = pk;
            } else {
                int oo = o0 - 512;
#pragma unroll
                for (int r = 0; r < 4; ++r) vws[(oo + r) * 4096 + n] = f2bf(v[r]);
            }
        }
    }
}

// ---------------- flash attention, LDS-staged K/V (staging-by-construction), split-K ----------------
// Thread (w,l) stages exactly the fragment slot that frag-reader (ki=w, lane=l) consumes:
// LDS write addr == read addr; global source == round-4's direct fragment addressing.
// Single buffer, two barriers per tile. Next tile's global loads issued under compute.
__global__ __launch_bounds__(256, 4) void k_attn(const unsigned short* __restrict__ qws,
                                                 const unsigned short* __restrict__ kws,
                                                 const unsigned short* __restrict__ vws,
                                                 float* __restrict__ opart,
                                                 float* __restrict__ oml) {
    __shared__ __align__(16) unsigned short sbuf[4096];   // K frags [0,2048), V frags [2048,4096)

    int h  = blockIdx.x;   // 0..7  fastest -> linear%8==h -> per-XCD head affinity
    int qs = blockIdx.y;   // 0..31 : 128-row tile (4 waves x 32)
    int sp = blockIdx.z;   // 0..3  : key split (1024 keys each)
    int t = threadIdx.x;
    int w = t >> 6, l = t & 63, lr = l & 15, lg = l >> 4;

    const unsigned short* qh = qws + h * 131072;
    const unsigned short* kh = kws + h * 131072;
    const unsigned short* vh = vws + h * 131072;

    int qb = qs * 128 + w * 32;
    short8 bq0 = *reinterpret_cast<const short8*>(qh + (qb + lr) * 32 + lg * 8);
    short8 bq1 = *reinterpret_cast<const short8*>(qh + (qb + 16 + lr) * 32 + lg * 8);

    f32x4 o00 = {0.f,0.f,0.f,0.f}, o01 = o00, o10 = o00, o11 = o00; // o[j][dsub]
    f32x4 la0 = {0.f,0.f,0.f,0.f}, la1 = {0.f,0.f,0.f,0.f};

    // ---- staging: thread (w,l) owns K frag ki=w lane l, and V seg sw=w lane l.
    // K frag ki reads key row kappa(lr)+off[ki], d = lg*8..+7  (round-4 addressing)
    int krow_s = 8 * (lr >> 2) + (lr & 3) + 4 * (w & 1) + 32 * (w >> 1);
    const unsigned short* ksrc = kh + krow_s * 32 + lg * 8;                 // + mt*2048
    unsigned short* kslot = &sbuf[w * 512 + l * 8];
    // V seg sw: kc = sw>>1, dsub = sw&1: d-row dsub*16+lr, keys kc*32 + lg*8..+7
    const unsigned short* vsrc = vh + ((w & 1) * 16 + lr) * 4096 + (w >> 1) * 32 + lg * 8;  // + mt*64
    unsigned short* vslot = &sbuf[2048 + w * 512 + l * 8];

    int mt0 = sp * 16, mt1 = mt0 + 16;

    // preload tile mt0 into registers
    ushort8 kreg = *reinterpret_cast<const ushort8*>(ksrc + mt0 * 2048);
    ushort8 vreg = *reinterpret_cast<const ushort8*>(vsrc + mt0 * 64);

    for (int mt = mt0; mt < mt1; ++mt) {
        __syncthreads();   // previous tile's readers are done
        *reinterpret_cast<ushort8*>(kslot) = kreg;
        *reinterpret_cast<ushort8*>(vslot) = vreg;
        __syncthreads();   // staged data visible to all waves

        if (mt + 1 < mt1) {  // issue next tile's global loads; latency hides under compute
            kreg = *reinterpret_cast<const ushort8*>(ksrc + (mt + 1) * 2048);
            vreg = *reinterpret_cast<const ushort8*>(vsrc + (mt + 1) * 64);
        }

        const unsigned short* kb = sbuf;
        short8 ka0 = *reinterpret_cast<const short8*>(kb + l * 8);
        short8 ka1 = *reinterpret_cast<const short8*>(kb + 512 + l * 8);
        short8 ka2 = *reinterpret_cast<const short8*>(kb + 1024 + l * 8);
        short8 ka3 = *reinterpret_cast<const short8*>(kb + 1536 + l * 8);
        const unsigned short* vbp = kb + 2048;
        short8 va00 = *reinterpret_cast<const short8*>(vbp + l * 8);          // kc0,dsub0
        short8 va10 = *reinterpret_cast<const short8*>(vbp + 512 + l * 8);    // kc0,dsub1
        short8 va01 = *reinterpret_cast<const short8*>(vbp + 1024 + l * 8);   // kc1,dsub0
        short8 va11 = *reinterpret_cast<const short8*>(vbp + 1536 + l * 8);   // kc1,dsub1

        const f32x4 z = {0.f, 0.f, 0.f, 0.f};
        f32x4 s00 = MFMA16(ka0, bq0, z);
        f32x4 s01 = MFMA16(ka1, bq0, z);
        f32x4 s02 = MFMA16(ka2, bq0, z);
        f32x4 s03 = MFMA16(ka3, bq0, z);
        f32x4 s10 = MFMA16(ka0, bq1, z);
        f32x4 s11 = MFMA16(ka1, bq1, z);
        f32x4 s12 = MFMA16(ka2, bq1, z);
        f32x4 s13 = MFMA16(ka3, bq1, z);

#pragma unroll
        for (int e = 0; e < 4; ++e) {
            s00[e] = fexp2(s00[e]); s01[e] = fexp2(s01[e]);
            s02[e] = fexp2(s02[e]); s03[e] = fexp2(s03[e]);
        }
        la0 += (s00 + s01) + (s02 + s03);
        union { u32x4 u; short8 s8; } p00, p01, p10, p11;
        p00.u[0] = cvtpk(s00[0], s00[1]); p00.u[1] = cvtpk(s00[2], s00[3]);
        p00.u[2] = cvtpk(s01[0], s01[1]); p00.u[3] = cvtpk(s01[2], s01[3]);
        p01.u[0] = cvtpk(s02[0], s02[1]); p01.u[1] = cvtpk(s02[2], s02[3]);
        p01.u[2] = cvtpk(s03[0], s03[1]); p01.u[3] = cvtpk(s03[2], s03[3]);

#pragma unroll
        for (int e = 0; e < 4; ++e) {
            s10[e] = fexp2(s10[e]); s11[e] = fexp2(s11[e]);
            s12[e] = fexp2(s12[e]); s13[e] = fexp2(s13[e]);
        }
        la1 += (s10 + s11) + (s12 + s13);
        p10.u[0] = cvtpk(s10[0], s10[1]); p10.u[1] = cvtpk(s10[2], s10[3]);
        p10.u[2] = cvtpk(s11[0], s11[1]); p10.u[3] = cvtpk(s11[2], s11[3]);
        p11.u[0] = cvtpk(s12[0], s12[1]); p11.u[1] = cvtpk(s12[2], s12[3]);
        p11.u[2] = cvtpk(s13[0], s13[1]); p11.u[3] = cvtpk(s13[2], s13[3]);

        o00 = MFMA16(va00, p00.s8, o00);
        o00 = MFMA16(va01, p01.s8, o00);
        o01 = MFMA16(va10, p00.s8, o01);
        o01 = MFMA16(va11, p01.s8, o01);
        o10 = MFMA16(va00, p10.s8, o10);
        o10 = MFMA16(va01, p11.s8, o10);
        o11 = MFMA16(va10, p10.s8, o11);
        o11 = MFMA16(va11, p11.s8, o11);
    }

    float ls0 = hsum4(la0);
    ls0 += __shfl_xor(ls0, 16);
    ls0 += __shfl_xor(ls0, 32);
    float ls1 = hsum4(la1);
    ls1 += __shfl_xor(ls1, 16);
    ls1 += __shfl_xor(ls1, 32);

    int q0 = qb + lr, q1 = qb + 16 + lr;
    float* ob0 = opart + ((h * 4096 + q0) * 4 + sp) * 32;
    float* ob1 = opart + ((h * 4096 + q1) * 4 + sp) * 32;
    __builtin_nontemporal_store(o00, reinterpret_cast<f32x4*>(ob0 + lg * 4));
    __builtin_nontemporal_store(o01, reinterpret_cast<f32x4*>(ob0 + 16 + lg * 4));
    __builtin_nontemporal_store(o10, reinterpret_cast<f32x4*>(ob1 + lg * 4));
    __builtin_nontemporal_store(o11, reinterpret_cast<f32x4*>(ob1 + 16 + lg * 4));
    oml[(h * 4096 + q0) * 4 + sp] = ls0;   // lg-duplicate writes, identical value
    oml[(h * 4096 + q1) * 4 + sp] = ls1;
}

// ---------------- combine split-K partials -> ao bf16 [n][256] ----------------
__global__ __launch_bounds__(256) void k_comb(const float* __restrict__ opart,
                                              const float* __restrict__ oml,
                                              unsigned short* __restrict__ ao) {
    int t = blockIdx.x * 256 + threadIdx.x;  // 131072 threads
    int hq = t >> 2;                         // 0..32767
    int dg = (t & 3) * 8;                    // d base
    f32x4 lv = *reinterpret_cast<const f32x4*>(oml + hq * 4);
    float inv = 1.0f / ((lv[0] + lv[1]) + (lv[2] + lv[3]));

    const float* ob = opart + hq * 128 + dg;
    f32x4 v0 = __builtin_nontemporal_load(reinterpret_cast<const f32x4*>(ob));
    f32x4 v1 = __builtin_nontemporal_load(reinterpret_cast<const f32x4*>(ob + 32));
    f32x4 v2 = __builtin_nontemporal_load(reinterpret_cast<const f32x4*>(ob + 64));
    f32x4 v3 = __builtin_nontemporal_load(reinterpret_cast<const f32x4*>(ob + 96));
    f32x4 acc0 = (v0 + v1) + (v2 + v3);
    v0 = __builtin_nontemporal_load(reinterpret_cast<const f32x4*>(ob + 4));
    v1 = __builtin_nontemporal_load(reinterpret_cast<const f32x4*>(ob + 36));
    v2 = __builtin_nontemporal_load(reinterpret_cast<const f32x4*>(ob + 68));
    v3 = __builtin_nontemporal_load(reinterpret_cast<const f32x4*>(ob + 100));
    f32x4 acc1 = (v0 + v1) + (v2 + v3);

    int h = hq >> 12, q = hq & 4095;
    unsigned short* dst = ao + q * 256 + h * 32 + dg;
    ushort4 pk;
    pk.x = f2bf(acc0[0] * inv); pk.y = f2bf(acc0[1] * inv);
    pk.z = f2bf(acc0[2] * inv); pk.w = f2bf(acc0[3] * inv);
    *reinterpret_cast<ushort4*>(dst) = pk;
    pk.x = f2bf(acc1[0] * inv); pk.y = f2bf(acc1[1] * inv);
    pk.z = f2bf(acc1[2] * inv); pk.w = f2bf(acc1[3] * inv);
    *reinterpret_cast<ushort4*>(dst + 4) = pk;
}

// ---------------- proj GEMM: [256][256] x ao^T + bias -> out fp32 [256][4096] ----------------
__global__ __launch_bounds__(256) void k_proj(const unsigned short* __restrict__ pwb,
                                              const unsigned short* __restrict__ ao,
                                              const float* __restrict__ bias,
                                              float* __restrict__ out) {
    int nt = blockIdx.x;   // 0..63
    int ot = blockIdx.y;   // 0..1
    int w = threadIdx.x >> 6;
    int l = threadIdx.x & 63;
    int lr = l & 15, lg = l >> 4;
    int obase = ot * 128 + w * 32;
    int nbase = nt * 64;

    f32x4 acc[2][4];
#pragma unroll
    for (int mi = 0; mi < 2; ++mi)
#pragma unroll
        for (int ni = 0; ni < 4; ++ni) acc[mi][ni] = (f32x4){0.f, 0.f, 0.f, 0.f};

#pragma unroll
    for (int ks = 0; ks < 8; ++ks) {
        short8 a[2], b[4];
#pragma unroll
        for (int mi = 0; mi < 2; ++mi)
            a[mi] = *reinterpret_cast<const short8*>(pwb + (obase + mi * 16 + lr) * 256 + ks * 32 + lg * 8);
#pragma unroll
        for (int ni = 0; ni < 4; ++ni)
            b[ni] = *reinterpret_cast<const short8*>(ao + (nbase + ni * 16 + lr) * 256 + ks * 32 + lg * 8);
#pragma unroll
        for (int mi = 0; mi < 2; ++mi)
#pragma unroll
            for (int ni = 0; ni < 4; ++ni)
                acc[mi][ni] = MFMA16(a[mi], b[ni], acc[mi][ni]);
    }

#pragma unroll
    for (int mi = 0; mi < 2; ++mi) {
        int o0 = obase + mi * 16 + lg * 4;
        float b0 = bias[o0 + 0], b1 = bias[o0 + 1], b2 = bias[o0 + 2], b3 = bias[o0 + 3];
#pragma unroll
        for (int ni = 0; ni < 4; ++ni) {
            int n = nbase + ni * 16 + lr;
            out[(o0 + 0) * 4096 + n] = acc[mi][ni][0] + b0;
            out[(o0 + 1) * 4096 + n] = acc[mi][ni][1] + b1;
            out[(o0 + 2) * 4096 + n] = acc[mi][ni][2] + b2;
            out[(o0 + 3) * 4096 + n] = acc[mi][ni][3] + b3;
        }
    }
}

extern "C" void kernel_launch(void* const* d_in, const int* in_sizes, int n_in,
                              void* d_out, int out_size, void* d_ws, size_t ws_size,
                              hipStream_t stream) {
    const float* x      = (const float*)d_in[0];
    const float* qkv_w  = (const float*)d_in[1];
    const float* proj_w = (const float*)d_in[2];
    const float* proj_b = (const float*)d_in[3];
    float* out = (float*)d_out;

    char* ws = (char*)d_ws;
    unsigned short* wqb = (unsigned short*)(ws + 0);         // 768*256*2   = 393216
    unsigned short* pwb = (unsigned short*)(ws + 393216);    // 256*256*2   = 131072
    unsigned short* xtb = (unsigned short*)(ws + 524288);    // 4096*256*2  = 2097152
    unsigned short* qws = (unsigned short*)(ws + 2621440);   // 8*4096*32*2 = 2097152
    unsigned short* kws = (unsigned short*)(ws + 4718592);   // 2097152
    unsigned short* vws = (unsigned short*)(ws + 6815744);   // 2097152
    unsigned short* ao  = (unsigned short*)(ws + 8912896);   // 4096*256*2  = 2097152
    float* opart        = (float*)(ws + 11010048);           // 8*4096*4*32*4 = 16777216
    float* oml          = (float*)(ws + 27787264);           // 8*4096*4*4   = 524288

    k_prep<<<512, 256, 0, stream>>>(qkv_w, proj_w, x, wqb, pwb, xtb);
    k_qkv<<<dim3(64, 6), 256, 0, stream>>>(wqb, xtb, qws, kws, vws);
    k_attn<<<dim3(8, 32, 4), 256, 0, stream>>>(qws, kws, vws, opart, oml);
    k_comb<<<512, 256, 0, stream>>>(opart, oml, ao);
    k_proj<<<dim3(64, 2), 256, 0, stream>>>(pwb, ao, proj_b, out);
}